// Round 9
// baseline (193.100 us; speedup 1.0000x reference)
//
#include <hip/hip_runtime.h>

// GraphCoordinator: out = x, except rows exactly equal to last_updated_param[p]
// (sequential running scan p=0..15) are replaced with learnable_param[p].
// Matches are ~16 of 1,000,000 rows. Single fused kernel:
//   - grid-stride 4-deep float4 memcpy x->out, CACHED loads and CACHED stores
//     (round-1 counters showed ~50% L3 hit on the streaming re-read: random
//     replacement retains ~cache/footprint. Cached write-back stores allow
//     this replay's dirty out-lines to be re-dirtied next replay before HBM
//     writeback — same ~50% potential saving on the write stream.)
//   - signature check: lane holds sig[tid&15] = last[tid&15][0]; row-start
//     element (lanes 0/32) broadcast via __shfl; 1 cmp + 1 ballot per m.
//     On a (rare) hit the wave replays the exact sequential p-loop with
//     full-row 32-lane ballot equality — running semantics in registers.
// Gating is a correct superset: a row can only be mutated mid-scan if it first
// matches some p, which requires an original element-0 signature hit.
// Floor: 512 MB read + 512 MB write ~= 163 us @ 6.3 TB/s copy ceiling.

#define F_DIM 128
#define P_DIM 16
#define UNROLL 4

typedef float f32x4 __attribute__((ext_vector_type(4)));

__global__ __launch_bounds__(256) void copy_fix_kernel(
    const float* __restrict__ x,
    const float* __restrict__ learn,
    const float* __restrict__ last,
    float* __restrict__ out,
    int total4)                      // n_rows * 32
{
    const int tid  = threadIdx.x;
    const int half = (tid >> 5) & 1;     // which half-wave (row owner)
    const int sl   = tid & 31;           // float4 slot within the row

    // Per-lane signature: last[tid&15][0] (lanes 16-31/48-63 duplicate 0-15).
    const float mysig = last[(tid & 15) * F_DIM];

    const f32x4* __restrict__ src = reinterpret_cast<const f32x4*>(x);
    f32x4*       __restrict__ dst = reinterpret_cast<f32x4*>(out);

    const int chunk   = 256 * UNROLL;                // 1024 float4/block-iter
    const int gstride = chunk * gridDim.x;
    const int total4_full = total4 & ~(chunk - 1);   // guard-free region

    int base = blockIdx.x * chunk;
    for (; base < total4_full; base += gstride) {
        const int i0 = base + tid;

        // Issue all UNROLL coalesced loads before any store (MLP).
        f32x4 v[UNROLL];
        #pragma unroll
        for (int m = 0; m < UNROLL; ++m)
            v[m] = src[i0 + m * 256];

        #pragma unroll
        for (int m = 0; m < UNROLL; ++m) {
            // Row starts sit in lanes 0 and 32 (base and m*256 are multiples
            // of 32 float4s = one row). Broadcast within each half-wave.
            const float bv = __shfl(v[m].x, tid & 32);
            if (__any(bv == mysig)) {
                // Cold path (~16 waves across the grid): exact sequential
                // running-semantics replay for this wave's 2 rows.
                for (int p = 0; p < P_DIM; ++p) {
                    const f32x4 lp =
                        *reinterpret_cast<const f32x4*>(&last[p * F_DIM + sl * 4]);
                    const bool eq = (v[m].x == lp.x) & (v[m].y == lp.y) &
                                    (v[m].z == lp.z) & (v[m].w == lp.w);
                    const unsigned long long bm = __ballot(eq);
                    const unsigned int mh = (unsigned int)(bm >> (half * 32));
                    if (mh == 0xFFFFFFFFu)
                        v[m] = *reinterpret_cast<const f32x4*>(
                                   &learn[p * F_DIM + sl * 4]);
                }
            }
        }

        #pragma unroll
        for (int m = 0; m < UNROLL; ++m)
            dst[i0 + m * 256] = v[m];
    }

    // Guarded tail (empty when total4 % chunk == 0, as for N=1M).
    for (; base < total4; base += gstride) {
        const int i0 = base + tid;
        #pragma unroll
        for (int m = 0; m < UNROLL; ++m) {
            const int i4 = i0 + m * 256;
            if (i4 >= total4) continue;
            f32x4 v = src[i4];
            const float bv = __shfl(v.x, tid & 32);
            if (__any(bv == mysig)) {
                for (int p = 0; p < P_DIM; ++p) {
                    const f32x4 lp =
                        *reinterpret_cast<const f32x4*>(&last[p * F_DIM + sl * 4]);
                    const bool eq = (v.x == lp.x) & (v.y == lp.y) &
                                    (v.z == lp.z) & (v.w == lp.w);
                    const unsigned long long bm = __ballot(eq);
                    const unsigned int mh = (unsigned int)(bm >> (half * 32));
                    if (mh == 0xFFFFFFFFu)
                        v = *reinterpret_cast<const f32x4*>(
                                &learn[p * F_DIM + sl * 4]);
                }
            }
            dst[i4] = v;
        }
    }
}

extern "C" void kernel_launch(void* const* d_in, const int* in_sizes, int n_in,
                              void* d_out, int out_size, void* d_ws, size_t ws_size,
                              hipStream_t stream) {
    // setup_inputs() order: x [N*F] f32, batch [N] i64 (unused),
    //                       learnable_param [P*F] f32, last_updated_param [P*F] f32
    const float* x     = (const float*)d_in[0];
    const float* learn = (const float*)d_in[2];
    const float* last  = (const float*)d_in[3];
    float*       out   = (float*)d_out;

    const int n_rows = in_sizes[0] / F_DIM;    // 1,000,000
    const int total4 = n_rows * (F_DIM / 4);   // 32,000,000 float4s

    copy_fix_kernel<<<2048, 256, 0, stream>>>(x, learn, last, out, total4);
}

// Round 10
// 182.975 us; speedup vs baseline: 1.0553x; 1.0553x over previous
//
#include <hip/hip_runtime.h>

// GraphCoordinator: out = x, except rows exactly equal to last_updated_param[p]
// (sequential running scan p=0..15) are replaced with learnable_param[p].
// Matches are ~16 of 1,000,000 rows. Single fused kernel (best measured
// config, round 6: 182.4 us ~= 89% of the 6.29 TB/s copy ceiling):
//   - grid-stride 4-deep NON-TEMPORAL float4 memcpy x->out (nt on BOTH
//     streams measured best: cached stores 193 us, cached loads ~186 us)
//   - the lane holding a row's element 0 ((tid&31)==0) compares it against
//     the 16 signatures last[p][0]; on a wave-level hit (__any, ~never taken)
//     the half-wave owning that row replays the exact sequential p-loop with
//     full-row 32-lane ballot equality — running semantics in registers.
// Gating is a correct superset: a row can only be mutated mid-scan if it
// first matches some p, which requires an original element-0 signature hit.
// Memory floor: 512 MB read + 512 MB write ~= 163 us @ 6.3 TB/s copy ceiling.

#define F_DIM 128
#define P_DIM 16
#define UNROLL 4

// Native clang vector type: __builtin_nontemporal_* rejects HIP_vector_type.
typedef float f32x4 __attribute__((ext_vector_type(4)));

__global__ __launch_bounds__(256) void copy_fix_kernel(
    const float* __restrict__ x,
    const float* __restrict__ learn,
    const float* __restrict__ last,
    float* __restrict__ out,
    int total4)                      // n_rows * 32
{
    const int tid  = threadIdx.x;
    const int half = (tid >> 5) & 1;   // which half of the wave (row owner)
    const int sl   = tid & 31;         // float4 slot within the row

    // 16 signatures: last[p][0]. Uniform addresses -> scalar loads.
    float sig[P_DIM];
    #pragma unroll
    for (int p = 0; p < P_DIM; ++p) sig[p] = last[p * F_DIM];

    const f32x4* __restrict__ src = reinterpret_cast<const f32x4*>(x);
    f32x4*       __restrict__ dst = reinterpret_cast<f32x4*>(out);

    const int chunk   = 256 * UNROLL;                // 1024 float4/block-iter
    const int gstride = chunk * gridDim.x;
    const int total4_full = total4 & ~(chunk - 1);   // guard-free region

    int base = blockIdx.x * chunk;
    for (; base < total4_full; base += gstride) {
        const int i0 = base + tid;

        // Issue all UNROLL coalesced loads before any store (MLP).
        f32x4 v[UNROLL];
        #pragma unroll
        for (int m = 0; m < UNROLL; ++m)
            v[m] = __builtin_nontemporal_load(&src[i0 + m * 256]);

        // Row-start lanes (sl==0) check element 0 against the 16 signatures.
        #pragma unroll
        for (int m = 0; m < UNROLL; ++m) {
            bool hit = false;
            if (sl == 0) {
                #pragma unroll
                for (int p = 0; p < P_DIM; ++p) hit |= (v[m].x == sig[p]);
            }
            if (__any(hit)) {
                // Cold path (~16 waves total across the whole grid): exact
                // sequential running-semantics replay for this wave's 2 rows.
                for (int p = 0; p < P_DIM; ++p) {
                    const f32x4 lp =
                        *reinterpret_cast<const f32x4*>(&last[p * F_DIM + sl * 4]);
                    const bool eq = (v[m].x == lp.x) & (v[m].y == lp.y) &
                                    (v[m].z == lp.z) & (v[m].w == lp.w);
                    const unsigned long long bm = __ballot(eq);
                    const unsigned int mh = (unsigned int)(bm >> (half * 32));
                    if (mh == 0xFFFFFFFFu)
                        v[m] = *reinterpret_cast<const f32x4*>(
                                   &learn[p * F_DIM + sl * 4]);
                }
            }
        }

        #pragma unroll
        for (int m = 0; m < UNROLL; ++m)
            __builtin_nontemporal_store(v[m], &dst[i0 + m * 256]);
    }

    // Guarded tail (empty when total4 % chunk == 0, as for N=1M).
    for (; base < total4; base += gstride) {
        const int i0 = base + tid;
        #pragma unroll
        for (int m = 0; m < UNROLL; ++m) {
            const int i4 = i0 + m * 256;
            if (i4 >= total4) continue;
            f32x4 v = __builtin_nontemporal_load(&src[i4]);
            bool hit = false;
            if (sl == 0) {
                #pragma unroll
                for (int p = 0; p < P_DIM; ++p) hit |= (v.x == sig[p]);
            }
            if (__any(hit)) {
                for (int p = 0; p < P_DIM; ++p) {
                    const f32x4 lp =
                        *reinterpret_cast<const f32x4*>(&last[p * F_DIM + sl * 4]);
                    const bool eq = (v.x == lp.x) & (v.y == lp.y) &
                                    (v.z == lp.z) & (v.w == lp.w);
                    const unsigned long long bm = __ballot(eq);
                    const unsigned int mh = (unsigned int)(bm >> (half * 32));
                    if (mh == 0xFFFFFFFFu)
                        v = *reinterpret_cast<const f32x4*>(
                                &learn[p * F_DIM + sl * 4]);
                }
            }
            __builtin_nontemporal_store(v, &dst[i4]);
        }
    }
}

extern "C" void kernel_launch(void* const* d_in, const int* in_sizes, int n_in,
                              void* d_out, int out_size, void* d_ws, size_t ws_size,
                              hipStream_t stream) {
    // setup_inputs() order: x [N*F] f32, batch [N] i64 (unused),
    //                       learnable_param [P*F] f32, last_updated_param [P*F] f32
    const float* x     = (const float*)d_in[0];
    const float* learn = (const float*)d_in[2];
    const float* last  = (const float*)d_in[3];
    float*       out   = (float*)d_out;

    const int n_rows = in_sizes[0] / F_DIM;    // 1,000,000
    const int total4 = n_rows * (F_DIM / 4);   // 32,000,000 float4s

    copy_fix_kernel<<<2048, 256, 0, stream>>>(x, learn, last, out, total4);
}